// Round 14
// baseline (269.460 us; speedup 1.0000x reference)
//
#include <hip/hip_runtime.h>

#define T_TASKS 64
#define B_SEQS 262144
#define BLOCK 256
#define CHUNKS 8
#define TPC 8                 // t-steps per chunk
#define PAIRS 32              // seq-pairs per block (64 seqs)

#define POS_BIG  3.402823466e+38f
#define NEG_BIG -3.402823466e+38f

// cap_table[id] = 0.01 * CAP_MATRIX[:,id], float4-padded: one LDS b128 per id.
__constant__ float c_capT[13][4] = {
    {0.00f, 0.00f, 0.00f, 0.f}, {0.33f, 0.33f, 0.33f, 0.f},
    {0.50f, 0.49f, 0.42f, 0.f}, {0.43f, 0.39f, 0.39f, 0.f},
    {0.56f, 0.58f, 0.44f, 0.f}, {0.67f, 0.67f, 0.52f, 0.f},
    {0.62f, 0.60f, 0.49f, 0.f}, {0.47f, 0.54f, 0.42f, 0.f},
    {0.50f, 0.52f, 0.45f, 0.f}, {0.51f, 0.52f, 0.46f, 0.f},
    {0.64f, 0.67f, 0.52f, 0.f}, {0.64f, 0.69f, 0.53f, 0.f},
    {0.68f, 0.71f, 0.56f, 0.f},
};

// scan step = clamp-composition (validated absmax=0 in R5/R11):
// med3(x, su?o:-INF, fa?o:+INF) == {max(x,o) | min(x,o) | x}
#define STEP(l, h, A, B)                          \
    l = __builtin_amdgcn_fmed3f(l, A, B);         \
    h = __builtin_amdgcn_fmed3f(h, A, B);

__global__ __launch_bounds__(BLOCK, 4) void trust_kernel(
    const int4* __restrict__ perf2,   // (T, B/2) int4 = perf for seq pair
    const int2* __restrict__ obs2,    // (T, B/2) int2 = obsids for seq pair
    const int*  __restrict__ predids, // (B)
    const float* __restrict__ betas,  // (3)
    const float* __restrict__ zetas,  // (3)
    float* __restrict__ out)          // (B)
{
    __shared__ float4 s_cap[13];
    __shared__ float  s_lh[CHUNKS][2 * PAIRS][7];   // 6 used + 1 pad (stride 7)

    if (threadIdx.x < 13)
        s_cap[threadIdx.x] = *(const float4*)&c_capT[threadIdx.x][0];
    __syncthreads();

    const int tid = threadIdx.x;
    const int ps  = tid & (PAIRS - 1);   // pair slot 0..31
    const int c   = tid >> 5;            // chunk 0..7 -> t in [c*8, c*8+8)
    const size_t rowStride = B_SEQS / 2;
    const size_t pair = (size_t)blockIdx.x * PAIRS + ps;
    const size_t base = (size_t)(c * TPC) * rowStride + pair;

    // ---- issue ALL 16 loads before any use; sched_barrier pins them ----
    int4 pf[TPC];
    int2 idv[TPC];
    #pragma unroll
    for (int i = 0; i < TPC; ++i)
        pf[i] = perf2[base + (size_t)i * rowStride];
    #pragma unroll
    for (int i = 0; i < TPC; ++i)
        idv[i] = obs2[base + (size_t)i * rowStride];
    __builtin_amdgcn_sched_barrier(0);   // nothing moves across: 16 loads in flight

    float la0=NEG_BIG, la1=NEG_BIG, la2=NEG_BIG;
    float ha0=POS_BIG, ha1=POS_BIG, ha2=POS_BIG;
    float lb0=NEG_BIG, lb1=NEG_BIG, lb2=NEG_BIG;
    float hb0=POS_BIG, hb1=POS_BIG, hb2=POS_BIG;

    #pragma unroll
    for (int i = 0; i < TPC; ++i) {      // consume in issue order: counted waits
        const float4 oa = s_cap[idv[i].x];
        const float4 ob = s_cap[idv[i].y];
        const bool sa = (pf[i].x == 0) && (pf[i].y != 0);
        const bool fa = (pf[i].x != 0) && (pf[i].y == 0);
        const bool sb = (pf[i].z == 0) && (pf[i].w != 0);
        const bool fb = (pf[i].z != 0) && (pf[i].w == 0);

        const float Aa0 = sa ? oa.x : NEG_BIG, Ba0 = fa ? oa.x : POS_BIG;
        const float Aa1 = sa ? oa.y : NEG_BIG, Ba1 = fa ? oa.y : POS_BIG;
        const float Aa2 = sa ? oa.z : NEG_BIG, Ba2 = fa ? oa.z : POS_BIG;
        const float Ab0 = sb ? ob.x : NEG_BIG, Bb0 = fb ? ob.x : POS_BIG;
        const float Ab1 = sb ? ob.y : NEG_BIG, Bb1 = fb ? ob.y : POS_BIG;
        const float Ab2 = sb ? ob.z : NEG_BIG, Bb2 = fb ? ob.z : POS_BIG;

        STEP(la0, ha0, Aa0, Ba0)
        STEP(la1, ha1, Aa1, Ba1)
        STEP(la2, ha2, Aa2, Ba2)
        STEP(lb0, hb0, Ab0, Bb0)
        STEP(lb1, hb1, Ab1, Bb1)
        STEP(lb2, hb2, Ab2, Bb2)
    }

    // seq 2*ps and 2*ps+1 of this block, chunk c
    float* da = &s_lh[c][2 * ps][0];
    da[0]=la0; da[1]=la1; da[2]=la2; da[3]=ha0; da[4]=ha1; da[5]=ha2;
    float* db = &s_lh[c][2 * ps + 1][0];
    db[0]=lb0; db[1]=lb1; db[2]=lb2; db[3]=hb0; db[4]=hb1; db[5]=hb2;
    __syncthreads();

    // ---- one thread per sequence: fold 8 chunks in t-order, logistic ----
    if (tid < 2 * PAIRS) {
        float x0 = 0.0f, x1 = 0.0f, x2 = 0.0f;
        #pragma unroll
        for (int cc = 0; cc < CHUNKS; ++cc) {
            const float* q = &s_lh[cc][tid][0];
            x0 = fminf(fmaxf(x0, q[0]), q[3]);
            x1 = fminf(fmaxf(x1, q[1]), q[4]);
            x2 = fminf(fmaxf(x2, q[2]), q[5]);
        }
        const size_t seq = (size_t)blockIdx.x * (2 * PAIRS) + tid;
        const int pid = predids[seq];
        const float4 r = s_cap[pid];

        const float q0 = betas[0] * (r.x - x0);
        const float q1 = betas[1] * (r.y - x1);
        const float q2 = betas[2] * (r.z - x2);

        const float t0 = powf(1.0f + expf(q0), -zetas[0]);
        const float t1 = powf(1.0f + expf(q1), -zetas[1]);
        const float t2 = powf(1.0f + expf(q2), -zetas[2]);

        out[seq] = t0 * t1 * t2;
    }
}

extern "C" void kernel_launch(void* const* d_in, const int* in_sizes, int n_in,
                              void* d_out, int out_size, void* d_ws, size_t ws_size,
                              hipStream_t stream) {
    // d_in[0] = inptasksobs (unused), d_in[4] = num_obs_tasks (unused)
    const int4*  perf2   = (const int4*)d_in[1];  // (T, B, 2) int32 as pair-int4
    const int2*  obs2    = (const int2*)d_in[2];  // (T, B, 1) int32 as pair-int2
    const int*   predids = (const int*)d_in[3];   // (B, 1) int32
    const float* betas   = (const float*)d_in[5];
    const float* zetas   = (const float*)d_in[6];
    float* out = (float*)d_out;

    const int blocks = B_SEQS / (2 * PAIRS);      // 4096 blocks, 64 seqs each
    trust_kernel<<<blocks, BLOCK, 0, stream>>>(perf2, obs2, predids, betas, zetas, out);
}

// Round 17
// 268.952 us; speedup vs baseline: 1.0019x; 1.0019x over previous
//
#include <hip/hip_runtime.h>

#define T_TASKS 64
#define B_SEQS 262144
#define BLOCK 256
#define CHUNKS 8
#define TPC 8                 // t-steps per chunk
#define PAIRS 32              // seq-pairs per block (64 seqs)

#define POS_BIG  3.402823466e+38f
#define NEG_BIG -3.402823466e+38f

typedef int   v4i __attribute__((ext_vector_type(4)));
typedef int   v2i __attribute__((ext_vector_type(2)));

// cap_table[id] = 0.01 * CAP_MATRIX[:,id], float4-padded: one LDS b128 per id.
__constant__ float c_capT[13][4] = {
    {0.00f, 0.00f, 0.00f, 0.f}, {0.33f, 0.33f, 0.33f, 0.f},
    {0.50f, 0.49f, 0.42f, 0.f}, {0.43f, 0.39f, 0.39f, 0.f},
    {0.56f, 0.58f, 0.44f, 0.f}, {0.67f, 0.67f, 0.52f, 0.f},
    {0.62f, 0.60f, 0.49f, 0.f}, {0.47f, 0.54f, 0.42f, 0.f},
    {0.50f, 0.52f, 0.45f, 0.f}, {0.51f, 0.52f, 0.46f, 0.f},
    {0.64f, 0.67f, 0.52f, 0.f}, {0.64f, 0.69f, 0.53f, 0.f},
    {0.68f, 0.71f, 0.56f, 0.f},
};

// scan step = clamp-composition (validated absmax=0 in R5/R11/R14):
// med3(x, su?o:-INF, fa?o:+INF) == {max(x,o) | min(x,o) | x}
#define STEP(l, h, A, B)                          \
    l = __builtin_amdgcn_fmed3f(l, A, B);         \
    h = __builtin_amdgcn_fmed3f(h, A, B);

// Inline-asm loads: the compiler CANNOT sink/interleave these, and their
// outputs are forced live -> 16 loads genuinely in flight per thread.
#define GLOAD4(dst, ptr) \
    asm volatile("global_load_dwordx4 %0, %1, off" : "=v"(dst) : "v"(ptr))
#define GLOAD2(dst, ptr) \
    asm volatile("global_load_dwordx2 %0, %1, off" : "=v"(dst) : "v"(ptr))

__global__ __launch_bounds__(BLOCK, 4) void trust_kernel(
    const v4i* __restrict__ perf2,    // (T, B/2) int4 = perf for seq pair
    const v2i* __restrict__ obs2,     // (T, B/2) int2 = obsids for seq pair
    const int* __restrict__ predids,  // (B)
    const float* __restrict__ betas,  // (3)
    const float* __restrict__ zetas,  // (3)
    float* __restrict__ out)          // (B)
{
    __shared__ float4 s_cap[13];
    __shared__ float  s_lh[CHUNKS][2 * PAIRS][7];   // 6 used + 1 pad

    if (threadIdx.x < 13)
        s_cap[threadIdx.x] = *(const float4*)&c_capT[threadIdx.x][0];
    __syncthreads();

    const int tid = threadIdx.x;
    const int ps  = tid & (PAIRS - 1);   // pair slot 0..31
    const int c   = tid >> 5;            // chunk 0..7 -> t in [c*8, c*8+8)
    const size_t rowStride = B_SEQS / 2;
    const size_t pair = (size_t)blockIdx.x * PAIRS + ps;
    const size_t base = (size_t)(c * TPC) * rowStride + pair;

    // ---- 16 inline-asm loads, all issued before any wait ----
    v4i pf0, pf1, pf2, pf3, pf4, pf5, pf6, pf7;
    v2i id0, id1, id2, id3, id4, id5, id6, id7;
    {
        const v4i* a = perf2 + base;
        GLOAD4(pf0, a);  a += rowStride;
        GLOAD4(pf1, a);  a += rowStride;
        GLOAD4(pf2, a);  a += rowStride;
        GLOAD4(pf3, a);  a += rowStride;
        GLOAD4(pf4, a);  a += rowStride;
        GLOAD4(pf5, a);  a += rowStride;
        GLOAD4(pf6, a);  a += rowStride;
        GLOAD4(pf7, a);
        const v2i* b = obs2 + base;
        GLOAD2(id0, b);  b += rowStride;
        GLOAD2(id1, b);  b += rowStride;
        GLOAD2(id2, b);  b += rowStride;
        GLOAD2(id3, b);  b += rowStride;
        GLOAD2(id4, b);  b += rowStride;
        GLOAD2(id5, b);  b += rowStride;
        GLOAD2(id6, b);  b += rowStride;
        GLOAD2(id7, b);
    }
    asm volatile("s_waitcnt vmcnt(0)" ::: "memory");
    __builtin_amdgcn_sched_barrier(0);   // rule #18: nothing hoists above wait

    float la0=NEG_BIG, la1=NEG_BIG, la2=NEG_BIG;
    float ha0=POS_BIG, ha1=POS_BIG, ha2=POS_BIG;
    float lb0=NEG_BIG, lb1=NEG_BIG, lb2=NEG_BIG;
    float hb0=POS_BIG, hb1=POS_BIG, hb2=POS_BIG;

#define CONSUME(pf, idv)                                                     \
    {                                                                        \
        const float4 oa = s_cap[(idv).x];                                    \
        const float4 ob = s_cap[(idv).y];                                    \
        const bool sa = ((pf).x == 0) && ((pf).y != 0);                      \
        const bool fa = ((pf).x != 0) && ((pf).y == 0);                      \
        const bool sb = ((pf).z == 0) && ((pf).w != 0);                      \
        const bool fb = ((pf).z != 0) && ((pf).w == 0);                      \
        const float Aa0 = sa ? oa.x : NEG_BIG, Ba0 = fa ? oa.x : POS_BIG;    \
        const float Aa1 = sa ? oa.y : NEG_BIG, Ba1 = fa ? oa.y : POS_BIG;    \
        const float Aa2 = sa ? oa.z : NEG_BIG, Ba2 = fa ? oa.z : POS_BIG;    \
        const float Ab0 = sb ? ob.x : NEG_BIG, Bb0 = fb ? ob.x : POS_BIG;    \
        const float Ab1 = sb ? ob.y : NEG_BIG, Bb1 = fb ? ob.y : POS_BIG;    \
        const float Ab2 = sb ? ob.z : NEG_BIG, Bb2 = fb ? ob.z : POS_BIG;    \
        STEP(la0, ha0, Aa0, Ba0)                                             \
        STEP(la1, ha1, Aa1, Ba1)                                             \
        STEP(la2, ha2, Aa2, Ba2)                                             \
        STEP(lb0, hb0, Ab0, Bb0)                                             \
        STEP(lb1, hb1, Ab1, Bb1)                                             \
        STEP(lb2, hb2, Ab2, Bb2)                                             \
    }

    CONSUME(pf0, id0)
    CONSUME(pf1, id1)
    CONSUME(pf2, id2)
    CONSUME(pf3, id3)
    CONSUME(pf4, id4)
    CONSUME(pf5, id5)
    CONSUME(pf6, id6)
    CONSUME(pf7, id7)
#undef CONSUME

    // seq 2*ps and 2*ps+1 of this block, chunk c
    float* da = &s_lh[c][2 * ps][0];
    da[0]=la0; da[1]=la1; da[2]=la2; da[3]=ha0; da[4]=ha1; da[5]=ha2;
    float* db = &s_lh[c][2 * ps + 1][0];
    db[0]=lb0; db[1]=lb1; db[2]=lb2; db[3]=hb0; db[4]=hb1; db[5]=hb2;
    __syncthreads();

    // ---- one thread per sequence: fold 8 chunks in t-order, logistic ----
    if (tid < 2 * PAIRS) {
        float x0 = 0.0f, x1 = 0.0f, x2 = 0.0f;
        #pragma unroll
        for (int cc = 0; cc < CHUNKS; ++cc) {
            const float* q = &s_lh[cc][tid][0];
            x0 = fminf(fmaxf(x0, q[0]), q[3]);
            x1 = fminf(fmaxf(x1, q[1]), q[4]);
            x2 = fminf(fmaxf(x2, q[2]), q[5]);
        }
        const size_t seq = (size_t)blockIdx.x * (2 * PAIRS) + tid;
        const int pid = predids[seq];
        const float4 r = s_cap[pid];

        const float q0 = betas[0] * (r.x - x0);
        const float q1 = betas[1] * (r.y - x1);
        const float q2 = betas[2] * (r.z - x2);

        const float t0 = powf(1.0f + expf(q0), -zetas[0]);
        const float t1 = powf(1.0f + expf(q1), -zetas[1]);
        const float t2 = powf(1.0f + expf(q2), -zetas[2]);

        out[seq] = t0 * t1 * t2;
    }
}

extern "C" void kernel_launch(void* const* d_in, const int* in_sizes, int n_in,
                              void* d_out, int out_size, void* d_ws, size_t ws_size,
                              hipStream_t stream) {
    // d_in[0] = inptasksobs (unused), d_in[4] = num_obs_tasks (unused)
    const v4i*   perf2   = (const v4i*)d_in[1];   // (T, B, 2) int32 as pair-int4
    const v2i*   obs2    = (const v2i*)d_in[2];   // (T, B, 1) int32 as pair-int2
    const int*   predids = (const int*)d_in[3];   // (B, 1) int32
    const float* betas   = (const float*)d_in[5];
    const float* zetas   = (const float*)d_in[6];
    float* out = (float*)d_out;

    const int blocks = B_SEQS / (2 * PAIRS);      // 4096 blocks, 64 seqs each
    trust_kernel<<<blocks, BLOCK, 0, stream>>>(perf2, obs2, predids, betas, zetas, out);
}

// Round 18
// 267.450 us; speedup vs baseline: 1.0075x; 1.0056x over previous
//
#include <hip/hip_runtime.h>

#define T_TASKS 64
#define B_SEQS 262144
#define BLOCK 256
#define CHUNKS 4              // 4 waves = 4 contiguous t-chunks of 16
#define TPC 16                // t-steps per chunk (per wave)
#define PAIRS 64              // pairs per block (128 seqs), 64 lanes = 64 pairs

#define POS_BIG  3.402823466e+38f
#define NEG_BIG -3.402823466e+38f

typedef int v4i __attribute__((ext_vector_type(4)));
typedef int v2i __attribute__((ext_vector_type(2)));

// cap_table[id] = 0.01 * CAP_MATRIX[:,id], float4-padded.
__constant__ float c_capT[13][4] = {
    {0.00f, 0.00f, 0.00f, 0.f}, {0.33f, 0.33f, 0.33f, 0.f},
    {0.50f, 0.49f, 0.42f, 0.f}, {0.43f, 0.39f, 0.39f, 0.f},
    {0.56f, 0.58f, 0.44f, 0.f}, {0.67f, 0.67f, 0.52f, 0.f},
    {0.62f, 0.60f, 0.49f, 0.f}, {0.47f, 0.54f, 0.42f, 0.f},
    {0.50f, 0.52f, 0.45f, 0.f}, {0.51f, 0.52f, 0.46f, 0.f},
    {0.64f, 0.67f, 0.52f, 0.f}, {0.64f, 0.69f, 0.53f, 0.f},
    {0.68f, 0.71f, 0.56f, 0.f},
};

// scan step = clamp-composition (validated absmax=0 in R5/R11/R14/R17):
// med3(x, su?o:-INF, fa?o:+INF) == {max(x,o) | min(x,o) | x}
#define STEP(l, h, A, B)                          \
    l = __builtin_amdgcn_fmed3f(l, A, B);         \
    h = __builtin_amdgcn_fmed3f(h, A, B);

// Inline-asm loads: wave-contiguous single-segment (64 lanes x consecutive
// elements). Compiler cannot sink/shrink these.
#define GLOAD4(dst, ptr) \
    asm volatile("global_load_dwordx4 %0, %1, off" : "=v"(dst) : "v"(ptr))
#define GLOAD2(dst, ptr) \
    asm volatile("global_load_dwordx2 %0, %1, off" : "=v"(dst) : "v"(ptr))
// Counted wait + scheduler fence (rule #18).
#define WAITC(N)                                                  \
    asm volatile("s_waitcnt vmcnt(" #N ")" ::: "memory");         \
    __builtin_amdgcn_sched_barrier(0);

__global__ __launch_bounds__(BLOCK, 4) void trust_kernel(
    const v4i* __restrict__ perf2,    // (T, B/2) int4 = perf for seq pair
    const v2i* __restrict__ obs2,     // (T, B/2) int2 = obsids for seq pair
    const int* __restrict__ predids,  // (B)
    const float* __restrict__ betas,  // (3)
    const float* __restrict__ zetas,  // (3)
    float* __restrict__ out)          // (B)
{
    __shared__ float4 s_cap[13];
    __shared__ float  s_lh[CHUNKS][2 * PAIRS][7];   // 6 used + 1 pad

    if (threadIdx.x < 13)
        s_cap[threadIdx.x] = *(const float4*)&c_capT[threadIdx.x][0];
    __syncthreads();

    const int tid = threadIdx.x;
    const int wv  = tid >> 6;            // wave = t-chunk 0..3, rows [16wv,16wv+16)
    const int ln  = tid & 63;            // lane = pair offset 0..63
    const size_t RS = B_SEQS / 2;        // row stride in pairs (131072)
    const size_t pairBase = (size_t)blockIdx.x * PAIRS;

    // wave-contiguous: all 64 lanes of a wave read consecutive int4/int2 of
    // ONE row -> each vmem instr is a single 1KB (perf) / 512B (obs) segment.
    const v4i* ap = perf2 + (size_t)(wv * TPC) * RS + pairBase + ln;
    const v2i* bp = obs2  + (size_t)(wv * TPC) * RS + pairBase + ln;

    v4i pfs0, pfs1, pfs2, pfs3;
    v2i ids0, ids1, ids2, ids3;

#define ISSUE(S)                                   \
    GLOAD4(pfs##S, ap);  ap += RS;                 \
    GLOAD2(ids##S, bp);  bp += RS;

    float la0=NEG_BIG, la1=NEG_BIG, la2=NEG_BIG;
    float ha0=POS_BIG, ha1=POS_BIG, ha2=POS_BIG;
    float lb0=NEG_BIG, lb1=NEG_BIG, lb2=NEG_BIG;
    float hb0=POS_BIG, hb1=POS_BIG, hb2=POS_BIG;

#define CONSUME(pf, idv)                                                     \
    {                                                                        \
        const float4 oa = s_cap[(idv).x];                                    \
        const float4 ob = s_cap[(idv).y];                                    \
        const bool sa = ((pf).x == 0) && ((pf).y != 0);                      \
        const bool fa = ((pf).x != 0) && ((pf).y == 0);                      \
        const bool sb = ((pf).z == 0) && ((pf).w != 0);                      \
        const bool fb = ((pf).z != 0) && ((pf).w == 0);                      \
        const float Aa0 = sa ? oa.x : NEG_BIG, Ba0 = fa ? oa.x : POS_BIG;    \
        const float Aa1 = sa ? oa.y : NEG_BIG, Ba1 = fa ? oa.y : POS_BIG;    \
        const float Aa2 = sa ? oa.z : NEG_BIG, Ba2 = fa ? oa.z : POS_BIG;    \
        const float Ab0 = sb ? ob.x : NEG_BIG, Bb0 = fb ? ob.x : POS_BIG;    \
        const float Ab1 = sb ? ob.y : NEG_BIG, Bb1 = fb ? ob.y : POS_BIG;    \
        const float Ab2 = sb ? ob.z : NEG_BIG, Bb2 = fb ? ob.z : POS_BIG;    \
        STEP(la0, ha0, Aa0, Ba0)                                             \
        STEP(la1, ha1, Aa1, Ba1)                                             \
        STEP(la2, ha2, Aa2, Ba2)                                             \
        STEP(lb0, hb0, Ab0, Bb0)                                             \
        STEP(lb1, hb1, Ab1, Bb1)                                             \
        STEP(lb2, hb2, Ab2, Bb2)                                             \
    }

    // 4-deep ring over 16 rows: 8 loads in flight, counted waits.
    ISSUE(0) ISSUE(1) ISSUE(2) ISSUE(3)                 // rows 0-3
    WAITC(6) CONSUME(pfs0, ids0) ISSUE(0)               // row 0, issue row 4
    WAITC(6) CONSUME(pfs1, ids1) ISSUE(1)               // row 1, issue row 5
    WAITC(6) CONSUME(pfs2, ids2) ISSUE(2)               // row 2, issue row 6
    WAITC(6) CONSUME(pfs3, ids3) ISSUE(3)               // row 3, issue row 7
    WAITC(6) CONSUME(pfs0, ids0) ISSUE(0)               // row 4, issue row 8
    WAITC(6) CONSUME(pfs1, ids1) ISSUE(1)               // row 5, issue row 9
    WAITC(6) CONSUME(pfs2, ids2) ISSUE(2)               // row 6, issue row 10
    WAITC(6) CONSUME(pfs3, ids3) ISSUE(3)               // row 7, issue row 11
    WAITC(6) CONSUME(pfs0, ids0) ISSUE(0)               // row 8, issue row 12
    WAITC(6) CONSUME(pfs1, ids1) ISSUE(1)               // row 9, issue row 13
    WAITC(6) CONSUME(pfs2, ids2) ISSUE(2)               // row 10, issue row 14
    WAITC(6) CONSUME(pfs3, ids3) ISSUE(3)               // row 11, issue row 15
    WAITC(6) CONSUME(pfs0, ids0)                        // row 12
    WAITC(4) CONSUME(pfs1, ids1)                        // row 13
    WAITC(2) CONSUME(pfs2, ids2)                        // row 14
    WAITC(0) CONSUME(pfs3, ids3)                        // row 15
#undef CONSUME
#undef ISSUE

    // lane ln owns pairs -> local seqs 2*ln, 2*ln+1 of chunk wv
    float* da = &s_lh[wv][2 * ln][0];
    da[0]=la0; da[1]=la1; da[2]=la2; da[3]=ha0; da[4]=ha1; da[5]=ha2;
    float* db = &s_lh[wv][2 * ln + 1][0];
    db[0]=lb0; db[1]=lb1; db[2]=lb2; db[3]=hb0; db[4]=hb1; db[5]=hb2;
    __syncthreads();

    // ---- one thread per sequence: fold 4 chunks in t-order, logistic ----
    if (tid < 2 * PAIRS) {
        float x0 = 0.0f, x1 = 0.0f, x2 = 0.0f;
        #pragma unroll
        for (int cc = 0; cc < CHUNKS; ++cc) {
            const float* q = &s_lh[cc][tid][0];
            x0 = fminf(fmaxf(x0, q[0]), q[3]);
            x1 = fminf(fmaxf(x1, q[1]), q[4]);
            x2 = fminf(fmaxf(x2, q[2]), q[5]);
        }
        const size_t seq = (size_t)blockIdx.x * (2 * PAIRS) + tid;
        const int pid = predids[seq];
        const float4 r = s_cap[pid];

        const float q0 = betas[0] * (r.x - x0);
        const float q1 = betas[1] * (r.y - x1);
        const float q2 = betas[2] * (r.z - x2);

        const float t0 = powf(1.0f + expf(q0), -zetas[0]);
        const float t1 = powf(1.0f + expf(q1), -zetas[1]);
        const float t2 = powf(1.0f + expf(q2), -zetas[2]);

        out[seq] = t0 * t1 * t2;
    }
}

extern "C" void kernel_launch(void* const* d_in, const int* in_sizes, int n_in,
                              void* d_out, int out_size, void* d_ws, size_t ws_size,
                              hipStream_t stream) {
    // d_in[0] = inptasksobs (unused), d_in[4] = num_obs_tasks (unused)
    const v4i*   perf2   = (const v4i*)d_in[1];   // (T, B, 2) int32 as pair-int4
    const v2i*   obs2    = (const v2i*)d_in[2];   // (T, B, 1) int32 as pair-int2
    const int*   predids = (const int*)d_in[3];   // (B, 1) int32
    const float* betas   = (const float*)d_in[5];
    const float* zetas   = (const float*)d_in[6];
    float* out = (float*)d_out;

    const int blocks = B_SEQS / (2 * PAIRS);      // 2048 blocks, 128 seqs each
    trust_kernel<<<blocks, BLOCK, 0, stream>>>(perf2, obs2, predids, betas, zetas, out);
}